// Round 16
// baseline (7177.217 us; speedup 1.0000x reference)
//
#include <hip/hip_runtime.h>
#include <hip/hip_bf16.h>
#include <cstdint>
#include <cstddef>

typedef float f32x4 __attribute__((ext_vector_type(4)));
typedef short s16x8 __attribute__((ext_vector_type(8)));

#define B_  256
#define T_  1024
#define D_  64
#define H_  512
#define O_  128
#define JW  16
#define NG  48

#define SLABW64 49152               // u64 words per slab: 16 blocks * 3072

// ---- LDS layout (bytes) ----
#define OFF_WGH   0                 // [48][512] bf16 W_hh rows (swizzled)
#define OFF_WGI2  49152             // [48][512] bf16 W_comb rows
#define OFF_WGIX  98304             // [48][64]  bf16 W_ih x-part
#define OFF_WDEC  104448            // [16][512] bf16 W_dec slice (cg<8)
#define OFF_W0S   120832
#define OFF_C0S   121024
#define OFF_BIHS  121216
#define OFF_BHHS  121408
#define OFF_BDECS 121600
#define OFF_SCR   121728            // 2 waves * 16x18 u16 scratch (1152B)
#define OFF_SCRF  122880            // 2 waves * 16x17 f32 scratch (2176B)
#define SMEM_BYTES 125056           // >80KB -> 1 WG/CU

// ---- workspace layout (bytes) ----
#define WS_WCOMB 0                  // [1536][512] bf16
#define WS_C0    1572864            // [1536] f32
#define WS_HSLAB 1579008            // 2 slabs * 393216 B (epoch-tagged h words)
#define WS_HSZ   786432
#define WS_DPR   2365440            // 8 bg * 16 u32 decoder progress
#define WS_CTL   786944             // memset span from WS_HSLAB

__device__ inline f32x4 mfma16(s16x8 a, s16x8 b, f32x4 c) {
  return __builtin_amdgcn_mfma_f32_16x16x32_bf16(a, b, c, 0, 0, 0);
}

__device__ inline unsigned short f2bf(float f) {
  __hip_bfloat16 h = __float2bfloat16(f);
  unsigned short u;
  __builtin_memcpy(&u, &h, sizeof(u));
  return u;
}

__device__ inline s16x8 cvt8(const float* s) {
  union { unsigned short h[8]; s16x8 v; } p;
#pragma unroll
  for (int e = 0; e < 8; ++e) p.h[e] = f2bf(s[e]);
  return p.v;
}

// B-fragment readers (rows K-contiguous, 16B-block XOR swizzle by (row&7)<<4)
__device__ inline s16x8 fragK512(const char* base, int n, int kc, int kg) {
  int byteoff = n * 1024 + (((kc * 64) + (kg * 16)) ^ ((n & 7) << 4));
  return *(const s16x8*)(base + byteoff);
}
__device__ inline s16x8 fragK64(const char* base, int n, int kc, int kg) {
  int byteoff = n * 128 + (((kc * 64) + (kg * 16)) ^ ((n & 7) << 4));
  return *(const s16x8*)(base + byteoff);
}

__device__ inline unsigned long long ld64a(const unsigned long long* p) {
  return __hip_atomic_load(p, __ATOMIC_RELAXED, __HIP_MEMORY_SCOPE_AGENT);
}
__device__ inline void st64a(unsigned long long* p, unsigned long long v) {
  __hip_atomic_store(p, v, __ATOMIC_RELAXED, __HIP_MEMORY_SCOPE_AGENT);
}
__device__ inline unsigned ld32a(const unsigned* p) {
  return __hip_atomic_load(p, __ATOMIC_RELAXED, __HIP_MEMORY_SCOPE_AGENT);
}
__device__ inline void st32a(unsigned* p, unsigned v) {
  __hip_atomic_store(p, v, __ATOMIC_RELAXED, __HIP_MEMORY_SCOPE_AGENT);
}

// 3 epoch-tagged words -> one 8-bf16 MFMA A-fragment (R9-proven)
__device__ inline s16x8 unpack3(unsigned long long w0, unsigned long long w1,
                                unsigned long long w2) {
  union { unsigned short u[8]; s16x8 v; } ua;
  ua.u[0] = (unsigned short)w0; ua.u[1] = (unsigned short)(w0 >> 16);
  ua.u[2] = (unsigned short)(w0 >> 32);
  ua.u[3] = (unsigned short)w1; ua.u[4] = (unsigned short)(w1 >> 16);
  ua.u[5] = (unsigned short)(w1 >> 32);
  ua.u[6] = (unsigned short)w2; ua.u[7] = (unsigned short)(w2 >> 16);
  return ua.v;
}

// group load: 8 kc * 3 words, coalesced (per kc the wave spans 1536B contiguous)
#define LOADG8(W, KC0)                                                    \
  {                                                                       \
    _Pragma("unroll") for (int k_ = 0; k_ < 8; ++k_) {                    \
      W[k_ * 3 + 0] = ld64a(rqL + ((KC0) + k_) * 192 + 0);                \
      W[k_ * 3 + 1] = ld64a(rqL + ((KC0) + k_) * 192 + 1);                \
      W[k_ * 3 + 2] = ld64a(rqL + ((KC0) + k_) * 192 + 2);                \
    }                                                                     \
  }

// verify group epochs; on mismatch re-load the whole group (1 RT per retry)
#define VERIFY8(W, KC0)                                                   \
  {                                                                       \
    for (;;) {                                                            \
      unsigned long long bad_ = 0;                                        \
      _Pragma("unroll") for (int i_ = 0; i_ < 24; ++i_)                   \
          bad_ |= (W[i_] >> 48) ^ tge;                                    \
      if (!__any((int)(bad_ != 0))) break;                                \
      if (--budget <= 0) break;                                           \
      LOADG8(W, KC0)                                                      \
    }                                                                     \
  }

#define UNPACKG8(W, KC0)                                                  \
  {                                                                       \
    _Pragma("unroll") for (int k_ = 0; k_ < 8; ++k_)                      \
        a[(KC0) + k_] =                                                   \
            unpack3(W[k_ * 3], W[k_ * 3 + 1], W[k_ * 3 + 2]);             \
  }

// ---------------- W_comb = W_ih[:,1:65] @ W_dec[:64,:]  (+ c0) ----------------
__global__ void wcomb_kernel(const float* __restrict__ W_ih, const float* __restrict__ W_dec,
                             const float* __restrict__ b_ih, const float* __restrict__ b_dec,
                             unsigned short* __restrict__ Wcomb, float* __restrict__ c0) {
  __shared__ float arow[64];
  int i = blockIdx.x;
  int tid = threadIdx.x;
  if (tid < 64) arow[tid] = W_ih[(size_t)i * 65 + 1 + tid];
  __syncthreads();
  for (int j = tid; j < H_; j += 256) {
    float acc = 0.f;
#pragma unroll 8
    for (int d = 0; d < 64; ++d) acc += arow[d] * W_dec[(size_t)d * H_ + j];
    Wcomb[(size_t)i * H_ + j] = f2bf(acc);
  }
  if (tid == 0) {
    float acc = b_ih[i];
    for (int d = 0; d < 64; ++d) acc += arow[d] * b_dec[d];
    c0[i] = acc;
  }
}

// ---- persistent recurrence: symmetric compute ring + decoupled decoder waves ----
__global__ __launch_bounds__(256, 1) void rnn_persist(
    const float* __restrict__ xs, const float* __restrict__ ts,
    const float* __restrict__ W_ih, const float* __restrict__ W_hh,
    const float* __restrict__ b_ih, const float* __restrict__ b_hh,
    const float* __restrict__ W_dec, const float* __restrict__ b_dec,
    const int* __restrict__ cutoffp,
    const unsigned short* __restrict__ Wcomb, const float* __restrict__ c0,
    unsigned long long* __restrict__ hslabE, unsigned* __restrict__ dpr,
    float* __restrict__ out) {
  extern __shared__ char sm[];
  const int tid = threadIdx.x;
  const int wave = tid >> 6, lane = tid & 63;
  const int jl = lane & 15, kg = lane >> 4;
  const int cutoff = *cutoffp;

  const int bg = blockIdx.x & 7;
  const int cg = blockIdx.x >> 3;
  const int b0 = bg * 32;
  const int j0 = cg * JW;

  // ---- one-time LDS fill (weights, swizzled; R2-proven layout) ----
  for (int u = tid; u < NG * 64; u += 256) {
    int r = u >> 6, blk = u & 63;
    int grow = (r >> 4) * H_ + j0 + (r & 15);
    s16x8 v = cvt8(W_hh + (size_t)grow * H_ + blk * 8);
    *(s16x8*)(sm + OFF_WGH + r * 1024 + ((blk * 16) ^ ((r & 7) << 4))) = v;
  }
  for (int u = tid; u < NG * 64; u += 256) {
    int r = u >> 6, blk = u & 63;
    int grow = (r >> 4) * H_ + j0 + (r & 15);
    s16x8 v = *(const s16x8*)(Wcomb + (size_t)grow * H_ + blk * 8);
    *(s16x8*)(sm + OFF_WGI2 + r * 1024 + ((blk * 16) ^ ((r & 7) << 4))) = v;
  }
  for (int u = tid; u < NG * 8; u += 256) {
    int r = u >> 3, blk = u & 7;
    int grow = (r >> 4) * H_ + j0 + (r & 15);
    s16x8 v = cvt8(W_ih + (size_t)grow * 65 + 1 + blk * 8);
    *(s16x8*)(sm + OFF_WGIX + r * 128 + ((blk * 16) ^ ((r & 7) << 4))) = v;
  }
  if (cg < 8) {
    for (int u = tid; u < 16 * 64; u += 256) {
      int r = u >> 6, blk = u & 63;
      s16x8 v = cvt8(W_dec + (size_t)(cg * 16 + r) * H_ + blk * 8);
      *(s16x8*)(sm + OFF_WDEC + r * 1024 + ((blk * 16) ^ ((r & 7) << 4))) = v;
    }
    if (tid < 16) ((float*)(sm + OFF_BDECS))[tid] = b_dec[cg * 16 + tid];
  }
  if (tid < NG) {
    int grow = (tid >> 4) * H_ + j0 + (tid & 15);
    ((float*)(sm + OFF_W0S))[tid]  = W_ih[(size_t)grow * 65];
    ((float*)(sm + OFF_C0S))[tid]  = c0[grow];
    ((float*)(sm + OFF_BIHS))[tid] = b_ih[grow];
    ((float*)(sm + OFF_BHHS))[tid] = b_hh[grow];
  }
  __syncthreads();

  int budget = 400000;

  // ===================== decoder waves (2,3): independent consumers =====================
  if (wave >= 2) {
    if (cg >= 8) return;
    const int dmt = wave - 2;
    const size_t blkb = (size_t)(bg * 2 + dmt) * 3072;
    const size_t laneoff = (size_t)kg * 48 + (size_t)jl * 3;
    float* scrF = (float*)(sm + OFF_SCRF) + dmt * 272;   // 16x17 f32
    const float bd = ((const float*)(sm + OFF_BDECS))[jl];
    const int oc = cg * 16 + jl;
    unsigned* myprog = dpr + bg * 16 + cg * 2 + dmt;
    s16x8 a[16];

    for (int v = 1; v <= T_; ++v) {
      const unsigned long long tge = (unsigned long long)(unsigned)v;   // epoch of h(v-1)
      const unsigned long long* rqL =
          hslabE + (size_t)((v - 1) & 1) * SLABW64 + blkb + laneoff;
      unsigned long long wA[24], wB[24];
      LOADG8(wA, 0)
      VERIFY8(wA, 0)
      LOADG8(wB, 8)
      UNPACKG8(wA, 0)
      VERIFY8(wB, 8)
      UNPACKG8(wB, 8)
      // reads of slab complete -> publish progress (fire-and-forget)
      if (lane == 0) st32a(myprog, (unsigned)v);

      f32x4 dacc{};
#pragma unroll
      for (int kc = 0; kc < 16; ++kc)
        dacc = mfma16(a[kc], fragK512(sm + OFF_WDEC, jl, kc, kg), dacc);
#pragma unroll
      for (int reg = 0; reg < 4; ++reg) {
        float vv = dacc[reg] + bd;
        if (oc >= D_) vv = fmaxf(vv, 0.001f);
        scrF[(kg * 4 + reg) * 17 + jl] = vv;
      }
      asm volatile("s_waitcnt lgkmcnt(0)" ::: "memory");
      __builtin_amdgcn_sched_barrier(0);
      {
        const int row = lane >> 2, seg = lane & 3;
        f32x4 ov = *(const f32x4*)(scrF + row * 17 + seg * 4);
        *(f32x4*)(out + ((size_t)(b0 + dmt * 16 + row) * T_ + (v - 1)) * O_ +
                  cg * 16 + seg * 4) = ov;
      }
    }
    return;
  }

  // ===================== compute waves (0,1): symmetric h-ring =====================
  const int mt = wave;
  const int rowg = b0 + mt * 16 + jl;
  const int hrow = b0 + mt * 16 + kg * 4;
  unsigned short* scr = (unsigned short*)(sm + OFF_SCR) + mt * 288;   // 16x18 u16

  const size_t blkb = (size_t)(bg * 2 + mt) * 3072;
  const size_t laneoff = (size_t)kg * 48 + (size_t)jl * 3;
  const int wi0 = lane;                          // writer slot = r*6 + fg*3 + pos
  const int wr0 = wi0 / 6, wk0 = wi0 % 6;
  const int wi1 = 64 + lane;
  const int wr1 = wi1 / 6, wk1 = wi1 % 6;

  const float* W0S  = (const float*)(sm + OFF_W0S);
  const float* C0S  = (const float*)(sm + OFF_C0S);
  const float* BIHS = (const float*)(sm + OFF_BIHS);
  const float* BHHS = (const float*)(sm + OFF_BHHS);
  const float w0r = W0S[jl],  w0z = W0S[16 + jl],  w0n = W0S[32 + jl];
  const float bir = BIHS[jl], biz = BIHS[16 + jl], bin_ = BIHS[32 + jl];
  const float c0r = C0S[jl],  c0z = C0S[16 + jl],  c0n = C0S[32 + jl];
  const float bhr = BHHS[jl], bhz = BHHS[16 + jl], bhn = BHHS[32 + jl];
  const unsigned* dprb = dpr + bg * 16;

  float hp[4] = {0.f, 0.f, 0.f, 0.f};
  s16x8 a[16];

  for (int t = 0; t < T_; ++t) {
    const bool use_x = (t < cutoff) || (t == 0);
    const unsigned long long tge = (unsigned long long)(unsigned)t;  // epoch of h(t-1)
    const unsigned long long epw = (unsigned long long)(t + 1) << 48;
    const unsigned long long* rqL =
        hslabE + (size_t)((t + 1) & 1) * SLABW64 + blkb + laneoff;
    unsigned long long* wq = hslabE + (size_t)(t & 1) * SLABW64 + blkb;

    // pre-issue decoder-progress load (flight hides under compute)
    unsigned dv = 0xFFFFFFFFu;
    if (t >= 2 && lane < 16) dv = ld32a(dprb + lane);

    float tsv[4];
#pragma unroll
    for (int reg = 0; reg < 4; ++reg) tsv[reg] = ts[(size_t)(hrow + reg) * T_ + t];

    f32x4 g0{}, g1{}, g2{}, i0{}, i1{}, i2{};
    if (use_x) {                                 // xs-side gi: pre-exchange
      s16x8 ax0 = cvt8(xs + ((size_t)rowg * T_ + t) * D_ + kg * 8);
      s16x8 ax1 = cvt8(xs + ((size_t)rowg * T_ + t) * D_ + 32 + kg * 8);
      i0 = mfma16(ax0, fragK64(sm + OFF_WGIX, jl,      0, kg), i0);
      i1 = mfma16(ax0, fragK64(sm + OFF_WGIX, 16 + jl, 0, kg), i1);
      i2 = mfma16(ax0, fragK64(sm + OFF_WGIX, 32 + jl, 0, kg), i2);
      i0 = mfma16(ax1, fragK64(sm + OFF_WGIX, jl,      1, kg), i0);
      i1 = mfma16(ax1, fragK64(sm + OFF_WGIX, 16 + jl, 1, kg), i1);
      i2 = mfma16(ax1, fragK64(sm + OFF_WGIX, 32 + jl, 1, kg), i2);
    }

    if (t > 0) {
      unsigned long long wA[24], wB[24];

#define MFMA_CL8(K0)                                                         \
      { _Pragma("unroll") for (int k_ = 0; k_ < 8; ++k_) {                   \
          int kc_ = (K0) + k_;                                               \
          g0 = mfma16(a[kc_], fragK512(sm + OFF_WGH, jl,      kc_, kg), g0); \
          g1 = mfma16(a[kc_], fragK512(sm + OFF_WGH, 16 + jl, kc_, kg), g1); \
          g2 = mfma16(a[kc_], fragK512(sm + OFF_WGH, 32 + jl, kc_, kg), g2); \
          if (!use_x) {                                                      \
            i0 = mfma16(a[kc_], fragK512(sm + OFF_WGI2, jl,      kc_, kg), i0); \
            i1 = mfma16(a[kc_], fragK512(sm + OFF_WGI2, 16 + jl, kc_, kg), i1); \
            i2 = mfma16(a[kc_], fragK512(sm + OFF_WGI2, 32 + jl, kc_, kg), i2); \
          } } }

      LOADG8(wA, 0)
      VERIFY8(wA, 0)        // absorbs the single overshoot
      LOADG8(wB, 8)         // issued fresh AFTER A passed; flight overlaps A-compute
      UNPACKG8(wA, 0)
      MFMA_CL8(0)
      VERIFY8(wB, 8)
      UNPACKG8(wB, 8)
      MFMA_CL8(8)
#undef MFMA_CL8
    }

    // GRU in-register (all 6 gate tiles share (lane,reg) layout)
    unsigned short hb[4];
#pragma unroll
    for (int reg = 0; reg < 4; ++reg) {
      const float xr = i0[reg] + tsv[reg] * w0r + (use_x ? bir : c0r) + g0[reg] + bhr;
      const float xz = i1[reg] + tsv[reg] * w0z + (use_x ? biz : c0z) + g1[reg] + bhz;
      const float an = i2[reg] + tsv[reg] * w0n + (use_x ? bin_ : c0n);
      const float gn = g2[reg] + bhn;
      const float r = 1.f / (1.f + __expf(-xr));
      const float z = 1.f / (1.f + __expf(-xz));
      const float e2 = __expf(2.f * (an + r * gn));
      const float n = 1.f - 2.f / (e2 + 1.f);
      const float hn = (1.f - z) * n + z * hp[reg];
      hp[reg] = hn;
      hb[reg] = f2bf(hn);
    }

    // backpressure: decoders must be done reading h(t-2) before we overwrite slab t&1
    if (t >= 2) {
      const unsigned tneed = (unsigned)(t - 1);
      for (;;) {
        unsigned v = (lane < 16) ? dv : tneed;
        if (__all((int)(v >= tneed))) break;
        if (--budget <= 0) break;
        if (lane < 16) dv = ld32a(dprb + lane);
      }
    }

    // transpose via LDS scratch (stride 18: conflict-free) -> epoch-tagged stores
#pragma unroll
    for (int reg = 0; reg < 4; ++reg) scr[(kg * 4 + reg) * 18 + jl] = hb[reg];
    asm volatile("s_waitcnt lgkmcnt(0)" ::: "memory");
    __builtin_amdgcn_sched_barrier(0);
    {
      const int fg = wk0 / 3, pos = wk0 % 3;
      const int cb = fg * 8 + pos * 3;
      unsigned long long v =
          (unsigned long long)scr[wr0 * 18 + cb] |
          ((unsigned long long)scr[wr0 * 18 + cb + 1] << 16) |
          (pos < 2 ? ((unsigned long long)scr[wr0 * 18 + cb + 2] << 32) : 0ull) |
          epw;
      st64a(wq + (size_t)(cg >> 1) * 192 +
                (size_t)((cg & 1) * 2 + fg) * 48 + (size_t)wr0 * 3 + pos, v);
    }
    if (lane < 32) {
      const int fg = wk1 / 3, pos = wk1 % 3;
      const int cb = fg * 8 + pos * 3;
      unsigned long long v =
          (unsigned long long)scr[wr1 * 18 + cb] |
          ((unsigned long long)scr[wr1 * 18 + cb + 1] << 16) |
          (pos < 2 ? ((unsigned long long)scr[wr1 * 18 + cb + 2] << 32) : 0ull) |
          epw;
      st64a(wq + (size_t)(cg >> 1) * 192 +
                (size_t)((cg & 1) * 2 + fg) * 48 + (size_t)wr1 * 3 + pos, v);
    }
  }
}

extern "C" void kernel_launch(void* const* d_in, const int* in_sizes, int n_in,
                              void* d_out, int out_size, void* d_ws, size_t ws_size,
                              hipStream_t stream) {
  const float* xs    = (const float*)d_in[0];
  const float* ts    = (const float*)d_in[1];
  const float* W_ih  = (const float*)d_in[2];
  const float* W_hh  = (const float*)d_in[3];
  const float* b_ih  = (const float*)d_in[4];
  const float* b_hh  = (const float*)d_in[5];
  const float* W_dec = (const float*)d_in[6];
  const float* b_dec = (const float*)d_in[7];
  const int* cutoff  = (const int*)d_in[8];
  float* out = (float*)d_out;

  char* ws = (char*)d_ws;
  unsigned short* Wcomb      = (unsigned short*)(ws + WS_WCOMB);
  float* c0                  = (float*)(ws + WS_C0);
  unsigned long long* hslabE = (unsigned long long*)(ws + WS_HSLAB);
  unsigned* dpr              = (unsigned*)(ws + WS_DPR);

  hipMemsetAsync(ws + WS_HSLAB, 0, WS_CTL, stream);   // zero epochs + dprog
  wcomb_kernel<<<1536, 256, 0, stream>>>(W_ih, W_dec, b_ih, b_dec, Wcomb, c0);
  hipFuncSetAttribute(reinterpret_cast<const void*>(rnn_persist),
                      hipFuncAttributeMaxDynamicSharedMemorySize, SMEM_BYTES);
  rnn_persist<<<256, 256, SMEM_BYTES, stream>>>(xs, ts, W_ih, W_hh, b_ih, b_hh,
                                                W_dec, b_dec, cutoff, Wcomb, c0,
                                                hslabE, dpr, out);
}

// Round 17
// 5439.021 us; speedup vs baseline: 1.3196x; 1.3196x over previous
//
#include <hip/hip_runtime.h>
#include <hip/hip_bf16.h>
#include <cstdint>
#include <cstddef>

typedef float f32x4 __attribute__((ext_vector_type(4)));
typedef short s16x8 __attribute__((ext_vector_type(8)));

#define B_  256
#define T_  1024
#define D_  64
#define H_  512
#define O_  128
#define JW  16
#define NG  48
#define SLP 12                      // pre-sample sleep ~64*12 cy ~0.32us

#define SLABW64 49152               // u64 words per slab: 16 blocks * 3072

// ---- LDS layout (bytes) ----
#define OFF_WGH   0                 // [48][512] bf16 W_hh rows (swizzled)
#define OFF_WGI2  49152             // [48][512] bf16 W_comb rows
#define OFF_WGIX  98304             // [48][64]  bf16 W_ih x-part
#define OFF_WDEC  104448            // [16][512] bf16 W_dec slice (cg>=24)
#define OFF_W0S   120832
#define OFF_C0S   121024
#define OFF_BIHS  121216
#define OFF_BHHS  121408
#define OFF_BDECS 121600
#define OFF_SCR   121728            // 2 waves * 16x18 u16 scratch
#define OFF_SCRF  122880            // 2 waves * 16x17 f32 scratch
#define SMEM_BYTES 125056           // >80KB -> 1 WG/CU

// ---- workspace layout (bytes) ----
#define WS_WCOMB 0                  // [1536][512] bf16
#define WS_C0    1572864            // [1536] f32
#define WS_HSLAB 1579008            // 2 slabs * 393216 B (epoch-tagged h words)
#define WS_HSZ   786432

__device__ inline f32x4 mfma16(s16x8 a, s16x8 b, f32x4 c) {
  return __builtin_amdgcn_mfma_f32_16x16x32_bf16(a, b, c, 0, 0, 0);
}

__device__ inline unsigned short f2bf(float f) {
  __hip_bfloat16 h = __float2bfloat16(f);
  unsigned short u;
  __builtin_memcpy(&u, &h, sizeof(u));
  return u;
}

__device__ inline s16x8 cvt8(const float* s) {
  union { unsigned short h[8]; s16x8 v; } p;
#pragma unroll
  for (int e = 0; e < 8; ++e) p.h[e] = f2bf(s[e]);
  return p.v;
}

// B-fragment readers (rows K-contiguous, 16B-block XOR swizzle by (row&7)<<4)
__device__ inline s16x8 fragK512(const char* base, int n, int kc, int kg) {
  int byteoff = n * 1024 + (((kc * 64) + (kg * 16)) ^ ((n & 7) << 4));
  return *(const s16x8*)(base + byteoff);
}
__device__ inline s16x8 fragK64(const char* base, int n, int kc, int kg) {
  int byteoff = n * 128 + (((kc * 64) + (kg * 16)) ^ ((n & 7) << 4));
  return *(const s16x8*)(base + byteoff);
}

__device__ inline unsigned long long ld64a(const unsigned long long* p) {
  return __hip_atomic_load(p, __ATOMIC_RELAXED, __HIP_MEMORY_SCOPE_AGENT);
}
__device__ inline void st64a(unsigned long long* p, unsigned long long v) {
  __hip_atomic_store(p, v, __ATOMIC_RELAXED, __HIP_MEMORY_SCOPE_AGENT);
}

// 3 epoch-tagged words -> one 8-bf16 MFMA A-fragment (R9-proven)
__device__ inline s16x8 unpack3(unsigned long long w0, unsigned long long w1,
                                unsigned long long w2) {
  union { unsigned short u[8]; s16x8 v; } ua;
  ua.u[0] = (unsigned short)w0; ua.u[1] = (unsigned short)(w0 >> 16);
  ua.u[2] = (unsigned short)(w0 >> 32);
  ua.u[3] = (unsigned short)w1; ua.u[4] = (unsigned short)(w1 >> 16);
  ua.u[5] = (unsigned short)(w1 >> 32);
  ua.u[6] = (unsigned short)w2; ua.u[7] = (unsigned short)(w2 >> 16);
  return ua.v;
}

// group load: 8 kc * 3 words, coalesced (per kc the wave spans 1536B contiguous)
#define LOADG8(W, KC0)                                                    \
  {                                                                       \
    _Pragma("unroll") for (int k_ = 0; k_ < 8; ++k_) {                    \
      W[k_ * 3 + 0] = ld64a(rqL + ((KC0) + k_) * 192 + 0);                \
      W[k_ * 3 + 1] = ld64a(rqL + ((KC0) + k_) * 192 + 1);                \
      W[k_ * 3 + 2] = ld64a(rqL + ((KC0) + k_) * 192 + 2);                \
    }                                                                     \
  }

#define BADOF(W) ({ unsigned long long b_ = 0;                            \
    _Pragma("unroll") for (int i_ = 0; i_ < 24; ++i_)                     \
        b_ |= (W[i_] >> 48) ^ tge; b_; })

#define UNPACKG8(W, KC0)                                                  \
  {                                                                       \
    _Pragma("unroll") for (int k_ = 0; k_ < 8; ++k_)                      \
        a[(KC0) + k_] =                                                   \
            unpack3(W[k_ * 3], W[k_ * 3 + 1], W[k_ * 3 + 2]);             \
  }

// ---------------- W_comb = W_ih[:,1:65] @ W_dec[:64,:]  (+ c0) ----------------
__global__ void wcomb_kernel(const float* __restrict__ W_ih, const float* __restrict__ W_dec,
                             const float* __restrict__ b_ih, const float* __restrict__ b_dec,
                             unsigned short* __restrict__ Wcomb, float* __restrict__ c0) {
  __shared__ float arow[64];
  int i = blockIdx.x;
  int tid = threadIdx.x;
  if (tid < 64) arow[tid] = W_ih[(size_t)i * 65 + 1 + tid];
  __syncthreads();
  for (int j = tid; j < H_; j += 256) {
    float acc = 0.f;
#pragma unroll 8
    for (int d = 0; d < 64; ++d) acc += arow[d] * W_dec[(size_t)d * H_ + j];
    Wcomb[(size_t)i * H_ + j] = f2bf(acc);
  }
  if (tid == 0) {
    float acc = b_ih[i];
    for (int d = 0; d < 64; ++d) acc += arow[d] * b_dec[d];
    c0[i] = acc;
  }
}

// ---------- persistent recurrence: late-sample joint-retry epoch exchange ----------
__global__ __launch_bounds__(128, 1) void rnn_persist(
    const float* __restrict__ xs, const float* __restrict__ ts,
    const float* __restrict__ W_ih, const float* __restrict__ W_hh,
    const float* __restrict__ b_ih, const float* __restrict__ b_hh,
    const float* __restrict__ W_dec, const float* __restrict__ b_dec,
    const int* __restrict__ cutoffp,
    const unsigned short* __restrict__ Wcomb, const float* __restrict__ c0,
    unsigned long long* __restrict__ hslabE, float* __restrict__ out) {
  extern __shared__ char sm[];
  const int tid = threadIdx.x;
  const int wave = tid >> 6, lane = tid & 63;
  const int jl = lane & 15, kg = lane >> 4;
  const int cutoff = *cutoffp;

  const int bg = blockIdx.x & 7;
  const int cg = blockIdx.x >> 3;
  const int b0 = bg * 32;
  const int j0 = cg * JW;

  // ---- one-time LDS fill (weights, swizzled; R2-proven layout) ----
  for (int u = tid; u < NG * 64; u += 128) {
    int r = u >> 6, blk = u & 63;
    int grow = (r >> 4) * H_ + j0 + (r & 15);
    s16x8 v = cvt8(W_hh + (size_t)grow * H_ + blk * 8);
    *(s16x8*)(sm + OFF_WGH + r * 1024 + ((blk * 16) ^ ((r & 7) << 4))) = v;
  }
  for (int u = tid; u < NG * 64; u += 128) {
    int r = u >> 6, blk = u & 63;
    int grow = (r >> 4) * H_ + j0 + (r & 15);
    s16x8 v = *(const s16x8*)(Wcomb + (size_t)grow * H_ + blk * 8);
    *(s16x8*)(sm + OFF_WGI2 + r * 1024 + ((blk * 16) ^ ((r & 7) << 4))) = v;
  }
  for (int u = tid; u < NG * 8; u += 128) {
    int r = u >> 3, blk = u & 7;
    int grow = (r >> 4) * H_ + j0 + (r & 15);
    s16x8 v = cvt8(W_ih + (size_t)grow * 65 + 1 + blk * 8);
    *(s16x8*)(sm + OFF_WGIX + r * 128 + ((blk * 16) ^ ((r & 7) << 4))) = v;
  }
  if (cg >= 24) {                                // decoders = cg 24..31 (group B producers)
    for (int u = tid; u < 16 * 64; u += 128) {
      int r = u >> 6, blk = u & 63;
      s16x8 v = cvt8(W_dec + (size_t)((cg - 24) * 16 + r) * H_ + blk * 8);
      *(s16x8*)(sm + OFF_WDEC + r * 1024 + ((blk * 16) ^ ((r & 7) << 4))) = v;
    }
    if (tid < 16) ((float*)(sm + OFF_BDECS))[tid] = b_dec[(cg - 24) * 16 + tid];
  }
  if (tid < NG) {
    int grow = (tid >> 4) * H_ + j0 + (tid & 15);
    ((float*)(sm + OFF_W0S))[tid]  = W_ih[(size_t)grow * 65];
    ((float*)(sm + OFF_C0S))[tid]  = c0[grow];
    ((float*)(sm + OFF_BIHS))[tid] = b_ih[grow];
    ((float*)(sm + OFF_BHHS))[tid] = b_hh[grow];
  }
  __syncthreads();

  const int mt = wave;                          // M-tile: 16 rows per wave
  const int rowg = b0 + mt * 16 + jl;           // A-frag row (per lane)
  const int hrow = b0 + mt * 16 + kg * 4;       // C-tile row base (per lane)
  unsigned short* scr = (unsigned short*)(sm + OFF_SCR) + mt * 288;   // 16x18 u16
  float* scrF = (float*)(sm + OFF_SCRF) + mt * 272;                   // 16x17 f32
  int budget = 200000;

  // slab bases (u64 units): block (bg,mt) = 3072 words, [kc][kg][jl][3]
  const size_t blkb = (size_t)(bg * 2 + mt) * 3072;
  const size_t laneoff = (size_t)kg * 48 + (size_t)jl * 3;
  const int wi0 = lane;                          // writer slot = r*6 + fg*3 + pos
  const int wr0 = wi0 / 6, wk0 = wi0 % 6;
  const int wi1 = 64 + lane;
  const int wr1 = wi1 / 6, wk1 = wi1 % 6;

  const float* W0S  = (const float*)(sm + OFF_W0S);
  const float* C0S  = (const float*)(sm + OFF_C0S);
  const float* BIHS = (const float*)(sm + OFF_BIHS);
  const float* BHHS = (const float*)(sm + OFF_BHHS);
  const float w0r = W0S[jl],  w0z = W0S[16 + jl],  w0n = W0S[32 + jl];
  const float bir = BIHS[jl], biz = BIHS[16 + jl], bin_ = BIHS[32 + jl];
  const float c0r = C0S[jl],  c0z = C0S[16 + jl],  c0n = C0S[32 + jl];
  const float bhr = BHHS[jl], bhz = BHHS[16 + jl], bhn = BHHS[32 + jl];

  const bool do_dec = (cg >= 24);
  const float bd = do_dec ? ((const float*)(sm + OFF_BDECS))[jl] : 0.f;

  float hp[4] = {0.f, 0.f, 0.f, 0.f};
  s16x8 a[16];

  for (int t = 0; t < T_; ++t) {
    const bool use_x = (t < cutoff) || (t == 0);
    const unsigned long long tge = (unsigned long long)(unsigned)t;  // epoch of h(t-1)
    const unsigned long long epw = (unsigned long long)(t + 1) << 48;
    const unsigned long long* rqL =
        hslabE + (size_t)((t + 1) & 1) * SLABW64 + blkb + laneoff;
    unsigned long long* wq = hslabE + (size_t)(t & 1) * SLABW64 + blkb;

    float tsv[4];
#pragma unroll
    for (int reg = 0; reg < 4; ++reg) tsv[reg] = ts[(size_t)(hrow + reg) * T_ + t];

    f32x4 g0{}, g1{}, g2{}, i0{}, i1{}, i2{};
    if (use_x) {                                 // xs-side gi: pre-exchange
      s16x8 ax0 = cvt8(xs + ((size_t)rowg * T_ + t) * D_ + kg * 8);
      s16x8 ax1 = cvt8(xs + ((size_t)rowg * T_ + t) * D_ + 32 + kg * 8);
      i0 = mfma16(ax0, fragK64(sm + OFF_WGIX, jl,      0, kg), i0);
      i1 = mfma16(ax0, fragK64(sm + OFF_WGIX, 16 + jl, 0, kg), i1);
      i2 = mfma16(ax0, fragK64(sm + OFF_WGIX, 32 + jl, 0, kg), i2);
      i0 = mfma16(ax1, fragK64(sm + OFF_WGIX, jl,      1, kg), i0);
      i1 = mfma16(ax1, fragK64(sm + OFF_WGIX, 16 + jl, 1, kg), i1);
      i2 = mfma16(ax1, fragK64(sm + OFF_WGIX, 32 + jl, 1, kg), i2);
    }

    if (t > 0) {
      unsigned long long wA[24], wB[24];

      // late sample: sleep past store-visibility, then load BOTH groups
      __builtin_amdgcn_s_sleep(SLP);
      LOADG8(wA, 0)
      LOADG8(wB, 8)
      // joint verify: one retry RT covers both groups
      for (;;) {
        unsigned long long bad = BADOF(wA) | BADOF(wB);
        if (!__any((int)(bad != 0))) break;
        if (--budget <= 0) break;
        LOADG8(wA, 0)
        LOADG8(wB, 8)
      }
      UNPACKG8(wA, 0)
      UNPACKG8(wB, 8)

#define MFMA_CL8(K0)                                                         \
      { _Pragma("unroll") for (int k_ = 0; k_ < 8; ++k_) {                   \
          int kc_ = (K0) + k_;                                               \
          g0 = mfma16(a[kc_], fragK512(sm + OFF_WGH, jl,      kc_, kg), g0); \
          g1 = mfma16(a[kc_], fragK512(sm + OFF_WGH, 16 + jl, kc_, kg), g1); \
          g2 = mfma16(a[kc_], fragK512(sm + OFF_WGH, 32 + jl, kc_, kg), g2); \
          if (!use_x) {                                                      \
            i0 = mfma16(a[kc_], fragK512(sm + OFF_WGI2, jl,      kc_, kg), i0); \
            i1 = mfma16(a[kc_], fragK512(sm + OFF_WGI2, 16 + jl, kc_, kg), i1); \
            i2 = mfma16(a[kc_], fragK512(sm + OFF_WGI2, 32 + jl, kc_, kg), i2); \
          } } }

      MFMA_CL8(0)
      MFMA_CL8(8)
#undef MFMA_CL8
    }

    // GRU in-register (all 6 gate tiles share (lane,reg) layout)
    unsigned short hb[4];
#pragma unroll
    for (int reg = 0; reg < 4; ++reg) {
      const float xr = i0[reg] + tsv[reg] * w0r + (use_x ? bir : c0r) + g0[reg] + bhr;
      const float xz = i1[reg] + tsv[reg] * w0z + (use_x ? biz : c0z) + g1[reg] + bhz;
      const float an = i2[reg] + tsv[reg] * w0n + (use_x ? bin_ : c0n);
      const float gn = g2[reg] + bhn;
      const float r = 1.f / (1.f + __expf(-xr));
      const float z = 1.f / (1.f + __expf(-xz));
      const float e2 = __expf(2.f * (an + r * gn));
      const float n = 1.f - 2.f / (e2 + 1.f);
      const float hn = (1.f - z) * n + z * hp[reg];
      hp[reg] = hn;
      hb[reg] = f2bf(hn);
    }

    // transpose via LDS scratch (stride 18) -> epoch-tagged coalesced stores
#pragma unroll
    for (int reg = 0; reg < 4; ++reg) scr[(kg * 4 + reg) * 18 + jl] = hb[reg];
    asm volatile("s_waitcnt lgkmcnt(0)" ::: "memory");
    __builtin_amdgcn_sched_barrier(0);
    {
      const int fg = wk0 / 3, pos = wk0 % 3;
      const int cb = fg * 8 + pos * 3;
      unsigned long long v =
          (unsigned long long)scr[wr0 * 18 + cb] |
          ((unsigned long long)scr[wr0 * 18 + cb + 1] << 16) |
          (pos < 2 ? ((unsigned long long)scr[wr0 * 18 + cb + 2] << 32) : 0ull) |
          epw;
      st64a(wq + (size_t)(cg >> 1) * 192 +
                (size_t)((cg & 1) * 2 + fg) * 48 + (size_t)wr0 * 3 + pos, v);
    }
    if (lane < 32) {
      const int fg = wk1 / 3, pos = wk1 % 3;
      const int cb = fg * 8 + pos * 3;
      unsigned long long v =
          (unsigned long long)scr[wr1 * 18 + cb] |
          ((unsigned long long)scr[wr1 * 18 + cb + 1] << 16) |
          (pos < 2 ? ((unsigned long long)scr[wr1 * 18 + cb + 2] << 32) : 0ull) |
          epw;
      st64a(wq + (size_t)(cg >> 1) * 192 +
                (size_t)((cg & 1) * 2 + fg) * 48 + (size_t)wr1 * 3 + pos, v);
    }

    // off-chain: decode step t-1 from register fragments (a[] = h(t-1))
    if (do_dec && t > 0) {
      f32x4 dacc{};
#pragma unroll
      for (int kc = 0; kc < 16; ++kc)
        dacc = mfma16(a[kc], fragK512(sm + OFF_WDEC, jl, kc, kg), dacc);
      const int oc = (cg - 24) * 16 + jl;
#pragma unroll
      for (int reg = 0; reg < 4; ++reg) {
        float vv = dacc[reg] + bd;
        if (oc >= D_) vv = fmaxf(vv, 0.001f);
        scrF[(kg * 4 + reg) * 17 + jl] = vv;
      }
      asm volatile("s_waitcnt lgkmcnt(0)" ::: "memory");
      __builtin_amdgcn_sched_barrier(0);
      {
        const int row = lane >> 2, seg = lane & 3;
        f32x4 ov = *(const f32x4*)(scrF + row * 17 + seg * 4);
        *(f32x4*)(out + ((size_t)(b0 + mt * 16 + row) * T_ + (t - 1)) * O_ +
                  (cg - 24) * 16 + seg * 4) = ov;
      }
    }
  }

  // epilogue: decode final step h(T-1)
  if (do_dec) {
    const unsigned long long tge = (unsigned long long)(unsigned)T_;
    const unsigned long long* rqL =
        hslabE + (size_t)((T_ - 1) & 1) * SLABW64 + blkb + laneoff;
    unsigned long long wA[24], wB[24];
    LOADG8(wA, 0)
    LOADG8(wB, 8)
    for (;;) {
      unsigned long long bad = BADOF(wA) | BADOF(wB);
      if (!__any((int)(bad != 0))) break;
      if (--budget <= 0) break;
      LOADG8(wA, 0)
      LOADG8(wB, 8)
    }
    UNPACKG8(wA, 0)
    UNPACKG8(wB, 8)
    f32x4 dacc{};
#pragma unroll
    for (int kc = 0; kc < 16; ++kc)
      dacc = mfma16(a[kc], fragK512(sm + OFF_WDEC, jl, kc, kg), dacc);
    const int oc = (cg - 24) * 16 + jl;
#pragma unroll
    for (int reg = 0; reg < 4; ++reg) {
      float vv = dacc[reg] + bd;
      if (oc >= D_) vv = fmaxf(vv, 0.001f);
      scrF[(kg * 4 + reg) * 17 + jl] = vv;
    }
    asm volatile("s_waitcnt lgkmcnt(0)" ::: "memory");
    __builtin_amdgcn_sched_barrier(0);
    {
      const int row = lane >> 2, seg = lane & 3;
      f32x4 ov = *(const f32x4*)(scrF + row * 17 + seg * 4);
      *(f32x4*)(out + ((size_t)(b0 + mt * 16 + row) * T_ + (T_ - 1)) * O_ +
                (cg - 24) * 16 + seg * 4) = ov;
    }
  }
}

extern "C" void kernel_launch(void* const* d_in, const int* in_sizes, int n_in,
                              void* d_out, int out_size, void* d_ws, size_t ws_size,
                              hipStream_t stream) {
  const float* xs    = (const float*)d_in[0];
  const float* ts    = (const float*)d_in[1];
  const float* W_ih  = (const float*)d_in[2];
  const float* W_hh  = (const float*)d_in[3];
  const float* b_ih  = (const float*)d_in[4];
  const float* b_hh  = (const float*)d_in[5];
  const float* W_dec = (const float*)d_in[6];
  const float* b_dec = (const float*)d_in[7];
  const int* cutoff  = (const int*)d_in[8];
  float* out = (float*)d_out;

  char* ws = (char*)d_ws;
  unsigned short* Wcomb      = (unsigned short*)(ws + WS_WCOMB);
  float* c0                  = (float*)(ws + WS_C0);
  unsigned long long* hslabE = (unsigned long long*)(ws + WS_HSLAB);

  hipMemsetAsync(ws + WS_HSLAB, 0, WS_HSZ, stream);   // zero epochs (replay-safe)
  wcomb_kernel<<<1536, 256, 0, stream>>>(W_ih, W_dec, b_ih, b_dec, Wcomb, c0);
  hipFuncSetAttribute(reinterpret_cast<const void*>(rnn_persist),
                      hipFuncAttributeMaxDynamicSharedMemorySize, SMEM_BYTES);
  rnn_persist<<<256, 128, SMEM_BYTES, stream>>>(xs, ts, W_ih, W_hh, b_ih, b_hh,
                                                W_dec, b_dec, cutoff, Wcomb, c0,
                                                hslabE, out);
}

// Round 18
// 5220.374 us; speedup vs baseline: 1.3748x; 1.0419x over previous
//
#include <hip/hip_runtime.h>
#include <hip/hip_bf16.h>
#include <cstdint>
#include <cstddef>

typedef float f32x4 __attribute__((ext_vector_type(4)));
typedef short s16x8 __attribute__((ext_vector_type(8)));

#define B_  256
#define T_  1024
#define D_  64
#define H_  512
#define O_  128
#define JW  16
#define NG  48

#define SLABW64 49152               // u64 words per slab: 16 blocks * 3072

// ---- LDS layout (bytes) ----
#define OFF_WGH   0                 // [3][16][16][4] 16B frags (W_hh)        49152
#define OFF_WGI2  49152             // [3][16][16][4] 16B frags (W_comb)     49152
#define OFF_WGIX  98304             // [3][2][16][4]  16B frags (W_ih x)      6144
#define OFF_WDEC  104448            // [16][16][4]    16B frags (W_dec)      16384
#define OFF_W0S   120832
#define OFF_C0S   121024
#define OFF_BIHS  121216
#define OFF_BHHS  121408
#define OFF_BDECS 121600
#define OFF_SCR   121728            // 2 waves * 16x18 u16 scratch
#define OFF_SCRF  122880            // 2 waves * 16x17 f32 scratch
#define SMEM_BYTES 125056           // >80KB -> 1 WG/CU

// ---- workspace layout (bytes) ----
#define WS_WCOMB 0                  // [1536][512] bf16
#define WS_C0    1572864            // [1536] f32
#define WS_HSLAB 1579008            // 2 slabs * 393216 B (epoch-tagged h words)
#define WS_HSZ   786432

__device__ inline f32x4 mfma16(s16x8 a, s16x8 b, f32x4 c) {
  return __builtin_amdgcn_mfma_f32_16x16x32_bf16(a, b, c, 0, 0, 0);
}

__device__ inline unsigned short f2bf(float f) {
  __hip_bfloat16 h = __float2bfloat16(f);
  unsigned short u;
  __builtin_memcpy(&u, &h, sizeof(u));
  return u;
}

__device__ inline s16x8 cvt8(const float* s) {
  union { unsigned short h[8]; s16x8 v; } p;
#pragma unroll
  for (int e = 0; e < 8; ++e) p.h[e] = f2bf(s[e]);
  return p.v;
}

// fragment-major W readers: per (g,kc) the wave reads 1024 contiguous bytes
// (16B per lane) -> conflict-free (2 lanes/bank/cycle)
__device__ inline s16x8 fragW(const char* base, int g, int kc, int jl, int kg) {
  int byteoff = ((((g * 16 + kc) * 16 + jl) * 4) + kg) * 16;
  return *(const s16x8*)(base + byteoff);
}
__device__ inline s16x8 fragWX(const char* base, int g, int kc, int jl, int kg) {
  int byteoff = ((((g * 2 + kc) * 16 + jl) * 4) + kg) * 16;
  return *(const s16x8*)(base + byteoff);
}
__device__ inline s16x8 fragWD(const char* base, int kc, int jl, int kg) {
  int byteoff = (((kc * 16 + jl) * 4) + kg) * 16;
  return *(const s16x8*)(base + byteoff);
}

__device__ inline unsigned long long ld64a(const unsigned long long* p) {
  return __hip_atomic_load(p, __ATOMIC_RELAXED, __HIP_MEMORY_SCOPE_AGENT);
}
__device__ inline void st64a(unsigned long long* p, unsigned long long v) {
  __hip_atomic_store(p, v, __ATOMIC_RELAXED, __HIP_MEMORY_SCOPE_AGENT);
}

// 3 epoch-tagged words -> one 8-bf16 MFMA A-fragment (R9-proven)
__device__ inline s16x8 unpack3(unsigned long long w0, unsigned long long w1,
                                unsigned long long w2) {
  union { unsigned short u[8]; s16x8 v; } ua;
  ua.u[0] = (unsigned short)w0; ua.u[1] = (unsigned short)(w0 >> 16);
  ua.u[2] = (unsigned short)(w0 >> 32);
  ua.u[3] = (unsigned short)w1; ua.u[4] = (unsigned short)(w1 >> 16);
  ua.u[5] = (unsigned short)(w1 >> 32);
  ua.u[6] = (unsigned short)w2; ua.u[7] = (unsigned short)(w2 >> 16);
  return ua.v;
}

// group load: 8 kc * 3 words, coalesced (per kc the wave spans 1536B contiguous)
#define LOADG8(W, KC0)                                                    \
  {                                                                       \
    _Pragma("unroll") for (int k_ = 0; k_ < 8; ++k_) {                    \
      W[k_ * 3 + 0] = ld64a(rqL + ((KC0) + k_) * 192 + 0);                \
      W[k_ * 3 + 1] = ld64a(rqL + ((KC0) + k_) * 192 + 1);                \
      W[k_ * 3 + 2] = ld64a(rqL + ((KC0) + k_) * 192 + 2);                \
    }                                                                     \
  }

// verify group epochs; on mismatch re-load the whole group (1 RT per retry)
#define VERIFY8(W, KC0)                                                   \
  {                                                                       \
    for (;;) {                                                            \
      unsigned long long bad_ = 0;                                        \
      _Pragma("unroll") for (int i_ = 0; i_ < 24; ++i_)                   \
          bad_ |= (W[i_] >> 48) ^ tge;                                    \
      if (!__any((int)(bad_ != 0))) break;                                \
      if (--budget <= 0) break;                                           \
      LOADG8(W, KC0)                                                      \
    }                                                                     \
  }

#define UNPACKG8(W, KC0)                                                  \
  {                                                                       \
    _Pragma("unroll") for (int k_ = 0; k_ < 8; ++k_)                      \
        a[(KC0) + k_] =                                                   \
            unpack3(W[k_ * 3], W[k_ * 3 + 1], W[k_ * 3 + 2]);             \
  }

// ---------------- W_comb = W_ih[:,1:65] @ W_dec[:64,:]  (+ c0) ----------------
__global__ void wcomb_kernel(const float* __restrict__ W_ih, const float* __restrict__ W_dec,
                             const float* __restrict__ b_ih, const float* __restrict__ b_dec,
                             unsigned short* __restrict__ Wcomb, float* __restrict__ c0) {
  __shared__ float arow[64];
  int i = blockIdx.x;
  int tid = threadIdx.x;
  if (tid < 64) arow[tid] = W_ih[(size_t)i * 65 + 1 + tid];
  __syncthreads();
  for (int j = tid; j < H_; j += 256) {
    float acc = 0.f;
#pragma unroll 8
    for (int d = 0; d < 64; ++d) acc += arow[d] * W_dec[(size_t)d * H_ + j];
    Wcomb[(size_t)i * H_ + j] = f2bf(acc);
  }
  if (tid == 0) {
    float acc = b_ih[i];
    for (int d = 0; d < 64; ++d) acc += arow[d] * b_dec[d];
    c0[i] = acc;
  }
}

// ---------- persistent recurrence: R15 exchange + conflict-free W layout ----------
__global__ __launch_bounds__(128, 1) void rnn_persist(
    const float* __restrict__ xs, const float* __restrict__ ts,
    const float* __restrict__ W_ih, const float* __restrict__ W_hh,
    const float* __restrict__ b_ih, const float* __restrict__ b_hh,
    const float* __restrict__ W_dec, const float* __restrict__ b_dec,
    const int* __restrict__ cutoffp,
    const unsigned short* __restrict__ Wcomb, const float* __restrict__ c0,
    unsigned long long* __restrict__ hslabE, float* __restrict__ out) {
  extern __shared__ char sm[];
  const int tid = threadIdx.x;
  const int wave = tid >> 6, lane = tid & 63;
  const int jl = lane & 15, kg = lane >> 4;
  const int cutoff = *cutoffp;

  const int bg = blockIdx.x & 7;
  const int cg = blockIdx.x >> 3;
  const int b0 = bg * 32;
  const int j0 = cg * JW;

  // ---- one-time LDS fill (fragment-major layout) ----
  for (int u = tid; u < NG * 64; u += 128) {      // W_hh
    int r = u >> 6, blk = u & 63;
    int g = r >> 4, jl_ = r & 15;
    int grow = g * H_ + j0 + jl_;
    s16x8 v = cvt8(W_hh + (size_t)grow * H_ + blk * 8);
    int kc = blk >> 2, kg_ = blk & 3;
    *(s16x8*)(sm + OFF_WGH + (((((g * 16 + kc) * 16 + jl_) * 4) + kg_) << 4)) = v;
  }
  for (int u = tid; u < NG * 64; u += 128) {      // W_comb (already bf16)
    int r = u >> 6, blk = u & 63;
    int g = r >> 4, jl_ = r & 15;
    int grow = g * H_ + j0 + jl_;
    s16x8 v = *(const s16x8*)(Wcomb + (size_t)grow * H_ + blk * 8);
    int kc = blk >> 2, kg_ = blk & 3;
    *(s16x8*)(sm + OFF_WGI2 + (((((g * 16 + kc) * 16 + jl_) * 4) + kg_) << 4)) = v;
  }
  for (int u = tid; u < NG * 8; u += 128) {       // W_ih x-part (K=64)
    int r = u >> 3, blk = u & 7;
    int g = r >> 4, jl_ = r & 15;
    int grow = g * H_ + j0 + jl_;
    s16x8 v = cvt8(W_ih + (size_t)grow * 65 + 1 + blk * 8);
    int kc = blk >> 2, kg_ = blk & 3;
    *(s16x8*)(sm + OFF_WGIX + (((((g * 2 + kc) * 16 + jl_) * 4) + kg_) << 4)) = v;
  }
  if (cg >= 24) {                                 // decoders = cg 24..31
    for (int u = tid; u < 16 * 64; u += 128) {    // W_dec slice
      int r = u >> 6, blk = u & 63;
      s16x8 v = cvt8(W_dec + (size_t)((cg - 24) * 16 + r) * H_ + blk * 8);
      int kc = blk >> 2, kg_ = blk & 3;
      *(s16x8*)(sm + OFF_WDEC + ((((kc * 16 + r) * 4) + kg_) << 4)) = v;
    }
    if (tid < 16) ((float*)(sm + OFF_BDECS))[tid] = b_dec[(cg - 24) * 16 + tid];
  }
  if (tid < NG) {
    int grow = (tid >> 4) * H_ + j0 + (tid & 15);
    ((float*)(sm + OFF_W0S))[tid]  = W_ih[(size_t)grow * 65];
    ((float*)(sm + OFF_C0S))[tid]  = c0[grow];
    ((float*)(sm + OFF_BIHS))[tid] = b_ih[grow];
    ((float*)(sm + OFF_BHHS))[tid] = b_hh[grow];
  }
  __syncthreads();

  const int mt = wave;                          // M-tile: 16 rows per wave
  const int rowg = b0 + mt * 16 + jl;           // A-frag row (per lane)
  const int hrow = b0 + mt * 16 + kg * 4;       // C-tile row base (per lane)
  unsigned short* scr = (unsigned short*)(sm + OFF_SCR) + mt * 288;   // 16x18 u16
  float* scrF = (float*)(sm + OFF_SCRF) + mt * 272;                   // 16x17 f32
  int budget = 200000;

  // slab bases (u64 units): block (bg,mt) = 3072 words, [kc][kg][jl][3]
  const size_t blkb = (size_t)(bg * 2 + mt) * 3072;
  const size_t laneoff = (size_t)kg * 48 + (size_t)jl * 3;
  const int wi0 = lane;                          // writer slot = r*6 + fg*3 + pos
  const int wr0 = wi0 / 6, wk0 = wi0 % 6;
  const int wi1 = 64 + lane;
  const int wr1 = wi1 / 6, wk1 = wi1 % 6;

  const float* W0S  = (const float*)(sm + OFF_W0S);
  const float* C0S  = (const float*)(sm + OFF_C0S);
  const float* BIHS = (const float*)(sm + OFF_BIHS);
  const float* BHHS = (const float*)(sm + OFF_BHHS);
  const float w0r = W0S[jl],  w0z = W0S[16 + jl],  w0n = W0S[32 + jl];
  const float bir = BIHS[jl], biz = BIHS[16 + jl], bin_ = BIHS[32 + jl];
  const float c0r = C0S[jl],  c0z = C0S[16 + jl],  c0n = C0S[32 + jl];
  const float bhr = BHHS[jl], bhz = BHHS[16 + jl], bhn = BHHS[32 + jl];

  const bool do_dec = (cg >= 24);
  const float bd = do_dec ? ((const float*)(sm + OFF_BDECS))[jl] : 0.f;

  float hp[4] = {0.f, 0.f, 0.f, 0.f};
  s16x8 a[16];

  for (int t = 0; t < T_; ++t) {
    const bool use_x = (t < cutoff) || (t == 0);
    const unsigned long long tge = (unsigned long long)(unsigned)t;  // epoch of h(t-1)
    const unsigned long long epw = (unsigned long long)(t + 1) << 48;
    const unsigned long long* rqL =
        hslabE + (size_t)((t + 1) & 1) * SLABW64 + blkb + laneoff;
    unsigned long long* wq = hslabE + (size_t)(t & 1) * SLABW64 + blkb;

    float tsv[4];
#pragma unroll
    for (int reg = 0; reg < 4; ++reg) tsv[reg] = ts[(size_t)(hrow + reg) * T_ + t];

    f32x4 g0{}, g1{}, g2{}, i0{}, i1{}, i2{};
    if (use_x) {                                 // xs-side gi: pre-exchange
      s16x8 ax0 = cvt8(xs + ((size_t)rowg * T_ + t) * D_ + kg * 8);
      s16x8 ax1 = cvt8(xs + ((size_t)rowg * T_ + t) * D_ + 32 + kg * 8);
      i0 = mfma16(ax0, fragWX(sm + OFF_WGIX, 0, 0, jl, kg), i0);
      i1 = mfma16(ax0, fragWX(sm + OFF_WGIX, 1, 0, jl, kg), i1);
      i2 = mfma16(ax0, fragWX(sm + OFF_WGIX, 2, 0, jl, kg), i2);
      i0 = mfma16(ax1, fragWX(sm + OFF_WGIX, 0, 1, jl, kg), i0);
      i1 = mfma16(ax1, fragWX(sm + OFF_WGIX, 1, 1, jl, kg), i1);
      i2 = mfma16(ax1, fragWX(sm + OFF_WGIX, 2, 1, jl, kg), i2);
    }

    if (t > 0) {
      unsigned long long wA[24], wB[24];

#define MFMA_CL8(K0)                                                         \
      { _Pragma("unroll") for (int k_ = 0; k_ < 8; ++k_) {                   \
          int kc_ = (K0) + k_;                                               \
          g0 = mfma16(a[kc_], fragW(sm + OFF_WGH, 0, kc_, jl, kg), g0);      \
          g1 = mfma16(a[kc_], fragW(sm + OFF_WGH, 1, kc_, jl, kg), g1);      \
          g2 = mfma16(a[kc_], fragW(sm + OFF_WGH, 2, kc_, jl, kg), g2);      \
          if (!use_x) {                                                      \
            i0 = mfma16(a[kc_], fragW(sm + OFF_WGI2, 0, kc_, jl, kg), i0);   \
            i1 = mfma16(a[kc_], fragW(sm + OFF_WGI2, 1, kc_, jl, kg), i1);   \
            i2 = mfma16(a[kc_], fragW(sm + OFF_WGI2, 2, kc_, jl, kg), i2);   \
          } } }

      LOADG8(wA, 0)
      VERIFY8(wA, 0)        // absorbs the single overshoot
      LOADG8(wB, 8)         // issued fresh AFTER A passed; flight overlaps A-compute
      UNPACKG8(wA, 0)
      MFMA_CL8(0)
      VERIFY8(wB, 8)
      UNPACKG8(wB, 8)
      MFMA_CL8(8)
#undef MFMA_CL8
    }

    // GRU in-register (all 6 gate tiles share (lane,reg) layout)
    unsigned short hb[4];
#pragma unroll
    for (int reg = 0; reg < 4; ++reg) {
      const float xr = i0[reg] + tsv[reg] * w0r + (use_x ? bir : c0r) + g0[reg] + bhr;
      const float xz = i1[reg] + tsv[reg] * w0z + (use_x ? biz : c0z) + g1[reg] + bhz;
      const float an = i2[reg] + tsv[reg] * w0n + (use_x ? bin_ : c0n);
      const float gn = g2[reg] + bhn;
      const float r = 1.f / (1.f + __expf(-xr));
      const float z = 1.f / (1.f + __expf(-xz));
      const float e2 = __expf(2.f * (an + r * gn));
      const float n = 1.f - 2.f / (e2 + 1.f);
      const float hn = (1.f - z) * n + z * hp[reg];
      hp[reg] = hn;
      hb[reg] = f2bf(hn);
    }

    // transpose via LDS scratch (stride 18) -> epoch-tagged coalesced stores
#pragma unroll
    for (int reg = 0; reg < 4; ++reg) scr[(kg * 4 + reg) * 18 + jl] = hb[reg];
    asm volatile("s_waitcnt lgkmcnt(0)" ::: "memory");
    __builtin_amdgcn_sched_barrier(0);
    {
      const int fg = wk0 / 3, pos = wk0 % 3;
      const int cb = fg * 8 + pos * 3;
      unsigned long long v =
          (unsigned long long)scr[wr0 * 18 + cb] |
          ((unsigned long long)scr[wr0 * 18 + cb + 1] << 16) |
          (pos < 2 ? ((unsigned long long)scr[wr0 * 18 + cb + 2] << 32) : 0ull) |
          epw;
      st64a(wq + (size_t)(cg >> 1) * 192 +
                (size_t)((cg & 1) * 2 + fg) * 48 + (size_t)wr0 * 3 + pos, v);
    }
    if (lane < 32) {
      const int fg = wk1 / 3, pos = wk1 % 3;
      const int cb = fg * 8 + pos * 3;
      unsigned long long v =
          (unsigned long long)scr[wr1 * 18 + cb] |
          ((unsigned long long)scr[wr1 * 18 + cb + 1] << 16) |
          (pos < 2 ? ((unsigned long long)scr[wr1 * 18 + cb + 2] << 32) : 0ull) |
          epw;
      st64a(wq + (size_t)(cg >> 1) * 192 +
                (size_t)((cg & 1) * 2 + fg) * 48 + (size_t)wr1 * 3 + pos, v);
    }

    // off-chain: decode step t-1 from register fragments (a[] = h(t-1))
    if (do_dec && t > 0) {
      f32x4 dacc{};
#pragma unroll
      for (int kc = 0; kc < 16; ++kc)
        dacc = mfma16(a[kc], fragWD(sm + OFF_WDEC, kc, jl, kg), dacc);
      const int oc = (cg - 24) * 16 + jl;
#pragma unroll
      for (int reg = 0; reg < 4; ++reg) {
        float vv = dacc[reg] + bd;
        if (oc >= D_) vv = fmaxf(vv, 0.001f);
        scrF[(kg * 4 + reg) * 17 + jl] = vv;
      }
      asm volatile("s_waitcnt lgkmcnt(0)" ::: "memory");
      __builtin_amdgcn_sched_barrier(0);
      {
        const int row = lane >> 2, seg = lane & 3;
        f32x4 ov = *(const f32x4*)(scrF + row * 17 + seg * 4);
        *(f32x4*)(out + ((size_t)(b0 + mt * 16 + row) * T_ + (t - 1)) * O_ +
                  (cg - 24) * 16 + seg * 4) = ov;
      }
    }
  }

  // epilogue: decode final step h(T-1)
  if (do_dec) {
    const unsigned long long tge = (unsigned long long)(unsigned)T_;
    const unsigned long long* rqL =
        hslabE + (size_t)((T_ - 1) & 1) * SLABW64 + blkb + laneoff;
    unsigned long long wA[24], wB[24];
    LOADG8(wA, 0)
    VERIFY8(wA, 0)
    LOADG8(wB, 8)
    UNPACKG8(wA, 0)
    VERIFY8(wB, 8)
    UNPACKG8(wB, 8)
    f32x4 dacc{};
#pragma unroll
    for (int kc = 0; kc < 16; ++kc)
      dacc = mfma16(a[kc], fragWD(sm + OFF_WDEC, kc, jl, kg), dacc);
    const int oc = (cg - 24) * 16 + jl;
#pragma unroll
    for (int reg = 0; reg < 4; ++reg) {
      float vv = dacc[reg] + bd;
      if (oc >= D_) vv = fmaxf(vv, 0.001f);
      scrF[(kg * 4 + reg) * 17 + jl] = vv;
    }
    asm volatile("s_waitcnt lgkmcnt(0)" ::: "memory");
    __builtin_amdgcn_sched_barrier(0);
    {
      const int row = lane >> 2, seg = lane & 3;
      f32x4 ov = *(const f32x4*)(scrF + row * 17 + seg * 4);
      *(f32x4*)(out + ((size_t)(b0 + mt * 16 + row) * T_ + (T_ - 1)) * O_ +
                (cg - 24) * 16 + seg * 4) = ov;
    }
  }
}

extern "C" void kernel_launch(void* const* d_in, const int* in_sizes, int n_in,
                              void* d_out, int out_size, void* d_ws, size_t ws_size,
                              hipStream_t stream) {
  const float* xs    = (const float*)d_in[0];
  const float* ts    = (const float*)d_in[1];
  const float* W_ih  = (const float*)d_in[2];
  const float* W_hh  = (const float*)d_in[3];
  const float* b_ih  = (const float*)d_in[4];
  const float* b_hh  = (const float*)d_in[5];
  const float* W_dec = (const float*)d_in[6];
  const float* b_dec = (const float*)d_in[7];
  const int* cutoff  = (const int*)d_in[8];
  float* out = (float*)d_out;

  char* ws = (char*)d_ws;
  unsigned short* Wcomb      = (unsigned short*)(ws + WS_WCOMB);
  float* c0                  = (float*)(ws + WS_C0);
  unsigned long long* hslabE = (unsigned long long*)(ws + WS_HSLAB);

  hipMemsetAsync(ws + WS_HSLAB, 0, WS_HSZ, stream);   // zero epochs (replay-safe)
  wcomb_kernel<<<1536, 256, 0, stream>>>(W_ih, W_dec, b_ih, b_dec, Wcomb, c0);
  hipFuncSetAttribute(reinterpret_cast<const void*>(rnn_persist),
                      hipFuncAttributeMaxDynamicSharedMemorySize, SMEM_BYTES);
  rnn_persist<<<256, 128, SMEM_BYTES, stream>>>(xs, ts, W_ih, W_hh, b_ih, b_hh,
                                                W_dec, b_dec, cutoff, Wcomb, c0,
                                                hslabE, out);
}

// Round 20
// 4893.102 us; speedup vs baseline: 1.4668x; 1.0669x over previous
//
#include <hip/hip_runtime.h>
#include <hip/hip_bf16.h>
#include <cstdint>
#include <cstddef>

typedef float f32x4 __attribute__((ext_vector_type(4)));
typedef short s16x8 __attribute__((ext_vector_type(8)));

#define B_  256
#define T_  1024
#define D_  64
#define H_  512
#define O_  128
#define JW  16
#define NG  48

#define SLABW64 49152               // u64 words per slab: 16 blocks * 3072

// ---- LDS layout (bytes) ----
#define OFF_WGH   0                 // [48][512] bf16 W_hh rows (swizzled)
#define OFF_WGI2  49152             // [48][512] bf16 W_comb rows
#define OFF_WGIX  98304             // [48][64]  bf16 W_ih x-part
#define OFF_WDEC  104448            // [16][512] bf16 W_dec slice (cg<8)
#define OFF_W0S   120832
#define OFF_C0S   121024
#define OFF_BIHS  121216
#define OFF_BHHS  121408
#define OFF_BDECS 121600
#define OFF_SCR   121728            // 2 waves * 16x16 u16 scratch (1024B)
#define SMEM_BYTES 122752           // >80KB -> 1 WG/CU

// ---- workspace layout (bytes) ----
#define WS_WCOMB 0                  // [1536][512] bf16
#define WS_C0    1572864            // [1536] f32
#define WS_HSLAB 1579008            // 2 slabs * 393216 B (epoch-tagged h words)
#define WS_HSZ   786432

__device__ inline f32x4 mfma16(s16x8 a, s16x8 b, f32x4 c) {
  return __builtin_amdgcn_mfma_f32_16x16x32_bf16(a, b, c, 0, 0, 0);
}

__device__ inline unsigned short f2bf(float f) {
  __hip_bfloat16 h = __float2bfloat16(f);
  unsigned short u;
  __builtin_memcpy(&u, &h, sizeof(u));
  return u;
}

__device__ inline s16x8 cvt8(const float* s) {
  union { unsigned short h[8]; s16x8 v; } p;
#pragma unroll
  for (int e = 0; e < 8; ++e) p.h[e] = f2bf(s[e]);
  return p.v;
}

// B-fragment readers (rows K-contiguous, 16B-block XOR swizzle by (row&7)<<4)
__device__ inline s16x8 fragK512(const char* base, int n, int kc, int kg) {
  int byteoff = n * 1024 + (((kc * 64) + (kg * 16)) ^ ((n & 7) << 4));
  return *(const s16x8*)(base + byteoff);
}
__device__ inline s16x8 fragK64(const char* base, int n, int kc, int kg) {
  int byteoff = n * 128 + (((kc * 64) + (kg * 16)) ^ ((n & 7) << 4));
  return *(const s16x8*)(base + byteoff);
}

__device__ inline unsigned long long ld64a(const unsigned long long* p) {
  return __hip_atomic_load(p, __ATOMIC_RELAXED, __HIP_MEMORY_SCOPE_AGENT);
}
__device__ inline void st64a(unsigned long long* p, unsigned long long v) {
  __hip_atomic_store(p, v, __ATOMIC_RELAXED, __HIP_MEMORY_SCOPE_AGENT);
}

// 3 epoch-tagged words -> one 8-bf16 MFMA A-fragment (R9-proven)
__device__ inline s16x8 unpack3(unsigned long long w0, unsigned long long w1,
                                unsigned long long w2) {
  union { unsigned short u[8]; s16x8 v; } ua;
  ua.u[0] = (unsigned short)w0; ua.u[1] = (unsigned short)(w0 >> 16);
  ua.u[2] = (unsigned short)(w0 >> 32);
  ua.u[3] = (unsigned short)w1; ua.u[4] = (unsigned short)(w1 >> 16);
  ua.u[5] = (unsigned short)(w1 >> 32);
  ua.u[6] = (unsigned short)w2; ua.u[7] = (unsigned short)(w2 >> 16);
  return ua.v;
}

// group load: 4 kc * 3 words, coalesced (per kc the wave spans 1536B contiguous)
#define LOADG(W, KC0)                                                     \
  {                                                                       \
    _Pragma("unroll") for (int k_ = 0; k_ < 4; ++k_) {                    \
      W[k_ * 3 + 0] = ld64a(rqL + ((KC0) + k_) * 192 + 0);                \
      W[k_ * 3 + 1] = ld64a(rqL + ((KC0) + k_) * 192 + 1);                \
      W[k_ * 3 + 2] = ld64a(rqL + ((KC0) + k_) * 192 + 2);                \
    }                                                                     \
  }

// verify group epochs; on mismatch re-load the whole group (1 RT per retry)
#define VERIFY(W, KC0)                                                    \
  {                                                                       \
    for (;;) {                                                            \
      unsigned long long bad_ = 0;                                        \
      _Pragma("unroll") for (int i_ = 0; i_ < 12; ++i_)                   \
          bad_ |= (W[i_] >> 48) ^ tge;                                    \
      if (!__any((int)(bad_ != 0))) break;                                \
      if (--budget <= 0) break;                                           \
      LOADG(W, KC0)                                                       \
    }                                                                     \
  }

#define UNPACKG(W, KC0)                                                   \
  {                                                                       \
    _Pragma("unroll") for (int k_ = 0; k_ < 4; ++k_)                      \
        a[(KC0) + k_] =                                                   \
            unpack3(W[k_ * 3], W[k_ * 3 + 1], W[k_ * 3 + 2]);             \
  }

// ---------------- W_comb = W_ih[:,1:65] @ W_dec[:64,:]  (+ c0) ----------------
__global__ void wcomb_kernel(const float* __restrict__ W_ih, const float* __restrict__ W_dec,
                             const float* __restrict__ b_ih, const float* __restrict__ b_dec,
                             unsigned short* __restrict__ Wcomb, float* __restrict__ c0) {
  __shared__ float arow[64];
  int i = blockIdx.x;
  int tid = threadIdx.x;
  if (tid < 64) arow[tid] = W_ih[(size_t)i * 65 + 1 + tid];
  __syncthreads();
  for (int j = tid; j < H_; j += 256) {
    float acc = 0.f;
#pragma unroll 8
    for (int d = 0; d < 64; ++d) acc += arow[d] * W_dec[(size_t)d * H_ + j];
    Wcomb[(size_t)i * H_ + j] = f2bf(acc);
  }
  if (tid == 0) {
    float acc = b_ih[i];
    for (int d = 0; d < 64; ++d) acc += arow[d] * b_dec[d];
    c0[i] = acc;
  }
}

// ---------- persistent recurrence: coalesced epoch-in-data, pipelined groups ----------
__global__ __launch_bounds__(128, 1) void rnn_persist(
    const float* __restrict__ xs, const float* __restrict__ ts,
    const float* __restrict__ W_ih, const float* __restrict__ W_hh,
    const float* __restrict__ b_ih, const float* __restrict__ b_hh,
    const float* __restrict__ W_dec, const float* __restrict__ b_dec,
    const int* __restrict__ cutoffp,
    const unsigned short* __restrict__ Wcomb, const float* __restrict__ c0,
    unsigned long long* __restrict__ hslabE, float* __restrict__ out) {
  extern __shared__ char sm[];
  const int tid = threadIdx.x;
  const int wave = tid >> 6, lane = tid & 63;
  const int jl = lane & 15, kg = lane >> 4;
  const int cutoff = *cutoffp;

  const int bg = blockIdx.x & 7;
  const int cg = blockIdx.x >> 3;
  const int b0 = bg * 32;
  const int j0 = cg * JW;

  // ---- one-time LDS fill (weights, swizzled; R2-proven layout) ----
  for (int u = tid; u < NG * 64; u += 128) {
    int r = u >> 6, blk = u & 63;
    int grow = (r >> 4) * H_ + j0 + (r & 15);
    s16x8 v = cvt8(W_hh + (size_t)grow * H_ + blk * 8);
    *(s16x8*)(sm + OFF_WGH + r * 1024 + ((blk * 16) ^ ((r & 7) << 4))) = v;
  }
  for (int u = tid; u < NG * 64; u += 128) {
    int r = u >> 6, blk = u & 63;
    int grow = (r >> 4) * H_ + j0 + (r & 15);
    s16x8 v = *(const s16x8*)(Wcomb + (size_t)grow * H_ + blk * 8);
    *(s16x8*)(sm + OFF_WGI2 + r * 1024 + ((blk * 16) ^ ((r & 7) << 4))) = v;
  }
  for (int u = tid; u < NG * 8; u += 128) {
    int r = u >> 3, blk = u & 7;
    int grow = (r >> 4) * H_ + j0 + (r & 15);
    s16x8 v = cvt8(W_ih + (size_t)grow * 65 + 1 + blk * 8);
    *(s16x8*)(sm + OFF_WGIX + r * 128 + ((blk * 16) ^ ((r & 7) << 4))) = v;
  }
  if (cg < 8) {
    for (int u = tid; u < 16 * 64; u += 128) {
      int r = u >> 6, blk = u & 63;
      s16x8 v = cvt8(W_dec + (size_t)(cg * 16 + r) * H_ + blk * 8);
      *(s16x8*)(sm + OFF_WDEC + r * 1024 + ((blk * 16) ^ ((r & 7) << 4))) = v;
    }
    if (tid < 16) ((float*)(sm + OFF_BDECS))[tid] = b_dec[cg * 16 + tid];
  }
  if (tid < NG) {
    int grow = (tid >> 4) * H_ + j0 + (tid & 15);
    ((float*)(sm + OFF_W0S))[tid]  = W_ih[(size_t)grow * 65];
    ((float*)(sm + OFF_C0S))[tid]  = c0[grow];
    ((float*)(sm + OFF_BIHS))[tid] = b_ih[grow];
    ((float*)(sm + OFF_BHHS))[tid] = b_hh[grow];
  }
  __syncthreads();

  const int mt = wave;                          // M-tile: 16 rows per wave
  const int rowg = b0 + mt * 16 + jl;           // A-frag row (per lane)
  const int hrow = b0 + mt * 16 + kg * 4;       // C-tile row base (per lane)
  unsigned short* scr = (unsigned short*)(sm + OFF_SCR) + mt * 256;
  int budget = 200000;

  // slab bases (u64 units): block (bg,mt) = 3072 words, [kc][kg][jl][3]
  const size_t blkb = (size_t)(bg * 2 + mt) * 3072;
  const size_t laneoff = (size_t)kg * 48 + (size_t)jl * 3;
  const int wi0 = lane;                          // writer slot = r*6 + fg*3 + pos
  const int wr0 = wi0 / 6, wk0 = wi0 % 6;
  const int wi1 = 64 + lane;
  const int wr1 = wi1 / 6, wk1 = wi1 % 6;

  const float* W0S  = (const float*)(sm + OFF_W0S);
  const float* C0S  = (const float*)(sm + OFF_C0S);
  const float* BIHS = (const float*)(sm + OFF_BIHS);
  const float* BHHS = (const float*)(sm + OFF_BHHS);
  const float w0r = W0S[jl],  w0z = W0S[16 + jl],  w0n = W0S[32 + jl];
  const float bir = BIHS[jl], biz = BIHS[16 + jl], bin_ = BIHS[32 + jl];
  const float c0r = C0S[jl],  c0z = C0S[16 + jl],  c0n = C0S[32 + jl];
  const float bhr = BHHS[jl], bhz = BHHS[16 + jl], bhn = BHHS[32 + jl];

  const bool do_dec = (cg < 8);
  const float bd = do_dec ? ((const float*)(sm + OFF_BDECS))[jl] : 0.f;
  const int oc = cg * 16 + jl;                  // decode out-col

  float hp[4] = {0.f, 0.f, 0.f, 0.f};

  for (int t = 0; t < T_; ++t) {
    const bool use_x = (t < cutoff) || (t == 0);
    const unsigned long long tge = (unsigned long long)(unsigned)t;  // epoch of h(t-1)
    const unsigned long long epw = (unsigned long long)(t + 1) << 48;
    const unsigned long long* rqL =
        hslabE + (size_t)((t + 1) & 1) * SLABW64 + blkb + laneoff;
    unsigned long long* wq = hslabE + (size_t)(t & 1) * SLABW64 + blkb;

    float tsv[4];
#pragma unroll
    for (int reg = 0; reg < 4; ++reg) tsv[reg] = ts[(size_t)(hrow + reg) * T_ + t];

    f32x4 g0{}, g1{}, g2{}, i0{}, i1{}, i2{};
    if (use_x) {                                 // xs-side gi: pre-exchange
      s16x8 ax0 = cvt8(xs + ((size_t)rowg * T_ + t) * D_ + kg * 8);
      s16x8 ax1 = cvt8(xs + ((size_t)rowg * T_ + t) * D_ + 32 + kg * 8);
      i0 = mfma16(ax0, fragK64(sm + OFF_WGIX, jl,      0, kg), i0);
      i1 = mfma16(ax0, fragK64(sm + OFF_WGIX, 16 + jl, 0, kg), i1);
      i2 = mfma16(ax0, fragK64(sm + OFF_WGIX, 32 + jl, 0, kg), i2);
      i0 = mfma16(ax1, fragK64(sm + OFF_WGIX, jl,      1, kg), i0);
      i1 = mfma16(ax1, fragK64(sm + OFF_WGIX, 16 + jl, 1, kg), i1);
      i2 = mfma16(ax1, fragK64(sm + OFF_WGIX, 32 + jl, 1, kg), i2);
    }

    s16x8 a[16];
    if (t > 0) {
      unsigned long long w0b[12], w1b[12];
      LOADG(w0b, 0)
      LOADG(w1b, 4)

#define MFMA_CL(K0)                                                          \
      { _Pragma("unroll") for (int k_ = 0; k_ < 4; ++k_) {                   \
          int kc_ = (K0) + k_;                                               \
          g0 = mfma16(a[kc_], fragK512(sm + OFF_WGH, jl,      kc_, kg), g0); \
          g1 = mfma16(a[kc_], fragK512(sm + OFF_WGH, 16 + jl, kc_, kg), g1); \
          g2 = mfma16(a[kc_], fragK512(sm + OFF_WGH, 32 + jl, kc_, kg), g2); \
          if (!use_x) {                                                      \
            i0 = mfma16(a[kc_], fragK512(sm + OFF_WGI2, jl,      kc_, kg), i0); \
            i1 = mfma16(a[kc_], fragK512(sm + OFF_WGI2, 16 + jl, kc_, kg), i1); \
            i2 = mfma16(a[kc_], fragK512(sm + OFF_WGI2, 32 + jl, kc_, kg), i2); \
          } } }

      VERIFY(w0b, 0)
      UNPACKG(w0b, 0)
      LOADG(w0b, 8)
      MFMA_CL(0)
      VERIFY(w1b, 4)
      UNPACKG(w1b, 4)
      LOADG(w1b, 12)
      MFMA_CL(4)
      VERIFY(w0b, 8)
      UNPACKG(w0b, 8)
      MFMA_CL(8)
      VERIFY(w1b, 12)
      UNPACKG(w1b, 12)
      MFMA_CL(12)
#undef MFMA_CL
    }

    // GRU in-register (all 6 gate tiles share (lane,reg) layout)
    unsigned short hb[4];
#pragma unroll
    for (int reg = 0; reg < 4; ++reg) {
      const float xr = i0[reg] + tsv[reg] * w0r + (use_x ? bir : c0r) + g0[reg] + bhr;
      const float xz = i1[reg] + tsv[reg] * w0z + (use_x ? biz : c0z) + g1[reg] + bhz;
      const float an = i2[reg] + tsv[reg] * w0n + (use_x ? bin_ : c0n);
      const float gn = g2[reg] + bhn;
      const float r = 1.f / (1.f + __expf(-xr));
      const float z = 1.f / (1.f + __expf(-xz));
      const float e2 = __expf(2.f * (an + r * gn));
      const float n = 1.f - 2.f / (e2 + 1.f);
      const float hn = (1.f - z) * n + z * hp[reg];
      hp[reg] = hn;
      hb[reg] = f2bf(hn);
    }

    // transpose via LDS scratch -> epoch-tagged coalesced stores (NO drain, NO flag)
#pragma unroll
    for (int reg = 0; reg < 4; ++reg) scr[(kg * 4 + reg) * 16 + jl] = hb[reg];
    asm volatile("s_waitcnt lgkmcnt(0)" ::: "memory");
    __builtin_amdgcn_sched_barrier(0);
    {
      // slot 0 (all lanes)
      const int fg = wk0 / 3, pos = wk0 % 3;
      const int cb = fg * 8 + pos * 3;
      unsigned long long v =
          (unsigned long long)scr[wr0 * 16 + cb] |
          ((unsigned long long)scr[wr0 * 16 + cb + 1] << 16) |
          (pos < 2 ? ((unsigned long long)scr[wr0 * 16 + cb + 2] << 32) : 0ull) |
          epw;
      st64a(wq + (size_t)(cg >> 1) * 192 +
                (size_t)((cg & 1) * 2 + fg) * 48 + (size_t)wr0 * 3 + pos, v);
    }
    if (lane < 32) {
      // slot 1 (lanes 0..31)
      const int fg = wk1 / 3, pos = wk1 % 3;
      const int cb = fg * 8 + pos * 3;
      unsigned long long v =
          (unsigned long long)scr[wr1 * 16 + cb] |
          ((unsigned long long)scr[wr1 * 16 + cb + 1] << 16) |
          (pos < 2 ? ((unsigned long long)scr[wr1 * 16 + cb + 2] << 32) : 0ull) |
          epw;
      st64a(wq + (size_t)(cg >> 1) * 192 +
                (size_t)((cg & 1) * 2 + fg) * 48 + (size_t)wr1 * 3 + pos, v);
    }

    // off-chain: decode step t-1 from register fragments (a[] = h(t-1))
    if (do_dec && t > 0) {
      f32x4 dacc{};
#pragma unroll
      for (int kc = 0; kc < 16; ++kc)
        dacc = mfma16(a[kc], fragK512(sm + OFF_WDEC, jl, kc, kg), dacc);
#pragma unroll
      for (int reg = 0; reg < 4; ++reg) {
        float vv = dacc[reg] + bd;
        if (oc >= D_) vv = fmaxf(vv, 0.001f);
        out[((size_t)(hrow + reg) * T_ + (t - 1)) * O_ + oc] = vv;
      }
    }
  }

  // epilogue: decode final step h(T-1)
  if (do_dec) {
    const unsigned long long tge = (unsigned long long)(unsigned)T_;
    const unsigned long long* rqL =
        hslabE + (size_t)((T_ - 1) & 1) * SLABW64 + blkb + laneoff;
    f32x4 dacc{};
    unsigned long long wv[12];
    s16x8 a[16];
#pragma unroll
    for (int grp = 0; grp < 4; ++grp) {
      LOADG(wv, grp * 4)
      VERIFY(wv, grp * 4)
      UNPACKG(wv, grp * 4)
#pragma unroll
      for (int k = 0; k < 4; ++k) {
        int kc = grp * 4 + k;
        dacc = mfma16(a[kc], fragK512(sm + OFF_WDEC, jl, kc, kg), dacc);
      }
    }
#pragma unroll
    for (int reg = 0; reg < 4; ++reg) {
      float vv = dacc[reg] + bd;
      if (oc >= D_) vv = fmaxf(vv, 0.001f);
      out[((size_t)(hrow + reg) * T_ + (T_ - 1)) * O_ + oc] = vv;
    }
  }
}

extern "C" void kernel_launch(void* const* d_in, const int* in_sizes, int n_in,
                              void* d_out, int out_size, void* d_ws, size_t ws_size,
                              hipStream_t stream) {
  const float* xs    = (const float*)d_in[0];
  const float* ts    = (const float*)d_in[1];
  const float* W_ih  = (const float*)d_in[2];
  const float* W_hh  = (const float*)d_in[3];
  const float* b_ih  = (const float*)d_in[4];
  const float* b_hh  = (const float*)d_in[5];
  const float* W_dec = (const float*)d_in[6];
  const float* b_dec = (const float*)d_in[7];
  const int* cutoff  = (const int*)d_in[8];
  float* out = (float*)d_out;

  char* ws = (char*)d_ws;
  unsigned short* Wcomb      = (unsigned short*)(ws + WS_WCOMB);
  float* c0                  = (float*)(ws + WS_C0);
  unsigned long long* hslabE = (unsigned long long*)(ws + WS_HSLAB);

  hipMemsetAsync(ws + WS_HSLAB, 0, WS_HSZ, stream);   // zero epochs (replay-safe)
  wcomb_kernel<<<1536, 256, 0, stream>>>(W_ih, W_dec, b_ih, b_dec, Wcomb, c0);
  hipFuncSetAttribute(reinterpret_cast<const void*>(rnn_persist),
                      hipFuncAttributeMaxDynamicSharedMemorySize, SMEM_BYTES);
  rnn_persist<<<256, 128, SMEM_BYTES, stream>>>(xs, ts, W_ih, W_hh, b_ih, b_hh,
                                                W_dec, b_dec, cutoff, Wcomb, c0,
                                                hslabE, out);
}